// Round 4
// baseline (3336.541 us; speedup 1.0000x reference)
//
#include <hip/hip_runtime.h>
#include <cstddef>
#include <cstdint>

#define EPS_BN 1e-5f
#define NBINS 4

// =====================================================================
// Tiled fp32 GEMM:  Y[r][o] = sum_ci X'[r][ci] * W[o][ci]   (Y = X' W^T)
// 64x64 tile, BK=16, 256 threads, 4x4 microtile/thread.
// FUSE_IN: X' = relu((X - mean)*scale) from st_in bins (prev layer BN).
// Epilogue: per-column sum / sumsq of raw Y accumulated into st_out bins.
// =====================================================================
template <bool FUSE_IN>
__global__ __launch_bounds__(256) void gemm_xwt(const float* __restrict__ X,
                                                const float* __restrict__ Wm,
                                                float* __restrict__ Y,
                                                int R, int Cin, int Cout,
                                                const float* __restrict__ st_in, int Rin,
                                                float* __restrict__ st_out) {
  __shared__ __align__(16) float Xs[16][68];   // [k][m], pad 68 -> conflict-free
  __shared__ __align__(16) float Ws[16][68];   // [k][n]
  __shared__ float sMean[512], sScale[512];    // only used when FUSE_IN
  const int t  = threadIdx.x;
  const int r0 = blockIdx.x << 6;
  const int n0 = blockIdx.y << 6;
  const int lk = t & 15;
  const int lm = t >> 4;
  const int tx = t & 15;
  const int ty = t >> 4;

  if constexpr (FUSE_IN) {
    const float inv = 1.f / (float)Rin;
    for (int k = t; k < Cin; k += 256) {
      float s = 0.f, q = 0.f;
#pragma unroll
      for (int bn = 0; bn < NBINS; ++bn) {
        s += st_in[bn * 2 * Cin + k];
        q += st_in[bn * 2 * Cin + Cin + k];
      }
      const float m  = s * inv;
      const float vr = fmaf(-m, m, q * inv);
      sMean[k]  = m;
      sScale[k] = rsqrtf(vr + EPS_BN);
    }
    __syncthreads();
  }

  float acc[4][4] = {{0.f, 0.f, 0.f, 0.f}, {0.f, 0.f, 0.f, 0.f},
                     {0.f, 0.f, 0.f, 0.f}, {0.f, 0.f, 0.f, 0.f}};
  for (int k0 = 0; k0 < Cin; k0 += 16) {
    const int k  = k0 + lk;
    const bool kv = (k < Cin);
#pragma unroll
    for (int q = 0; q < 4; ++q) {
      const int m = lm + (q << 4);
      const int r = r0 + m;
      float xv = (kv && r < R) ? X[(size_t)r * Cin + k] : 0.f;
      if constexpr (FUSE_IN) {
        if (kv && r < R) xv = fmaxf(0.f, (xv - sMean[k]) * sScale[k]);
      }
      Xs[lk][m] = xv;
      const int n = n0 + m;
      Ws[lk][m] = (kv && n < Cout) ? Wm[(size_t)n * Cin + k] : 0.f;
    }
    __syncthreads();
#pragma unroll
    for (int kk = 0; kk < 16; ++kk) {
      const float4 a = *(const float4*)(&Xs[kk][ty << 2]);
      const float4 b = *(const float4*)(&Ws[kk][tx << 2]);
      acc[0][0] = fmaf(a.x, b.x, acc[0][0]);
      acc[0][1] = fmaf(a.x, b.y, acc[0][1]);
      acc[0][2] = fmaf(a.x, b.z, acc[0][2]);
      acc[0][3] = fmaf(a.x, b.w, acc[0][3]);
      acc[1][0] = fmaf(a.y, b.x, acc[1][0]);
      acc[1][1] = fmaf(a.y, b.y, acc[1][1]);
      acc[1][2] = fmaf(a.y, b.z, acc[1][2]);
      acc[1][3] = fmaf(a.y, b.w, acc[1][3]);
      acc[2][0] = fmaf(a.z, b.x, acc[2][0]);
      acc[2][1] = fmaf(a.z, b.y, acc[2][1]);
      acc[2][2] = fmaf(a.z, b.z, acc[2][2]);
      acc[2][3] = fmaf(a.z, b.w, acc[2][3]);
      acc[3][0] = fmaf(a.w, b.x, acc[3][0]);
      acc[3][1] = fmaf(a.w, b.y, acc[3][1]);
      acc[3][2] = fmaf(a.w, b.z, acc[3][2]);
      acc[3][3] = fmaf(a.w, b.w, acc[3][3]);
    }
    __syncthreads();
  }
  // store Y
#pragma unroll
  for (int i = 0; i < 4; ++i) {
    const int r = r0 + (ty << 2) + i;
    if (r < R) {
#pragma unroll
      for (int j = 0; j < 4; ++j) {
        const int n = n0 + (tx << 2) + j;
        if (n < Cout) Y[(size_t)r * Cout + n] = acc[i][j];
      }
    }
  }
  // epilogue: per-column partials -> LDS reduce -> binned atomics
  float4 sj, qj;
  {
    float s, q;
#define COLP(J, FLD)                                                        \
    s = acc[0][J] + acc[1][J] + acc[2][J] + acc[3][J];                      \
    q = acc[0][J] * acc[0][J];                                              \
    q = fmaf(acc[1][J], acc[1][J], q);                                      \
    q = fmaf(acc[2][J], acc[2][J], q);                                      \
    q = fmaf(acc[3][J], acc[3][J], q);                                      \
    sj.FLD = s; qj.FLD = q;
    COLP(0, x) COLP(1, y) COLP(2, z) COLP(3, w)
#undef COLP
  }
  *(float4*)(&Xs[ty][tx << 2]) = sj;
  *(float4*)(&Ws[ty][tx << 2]) = qj;
  __syncthreads();
  if (t < 64) {
    float s = 0.f, q = 0.f;
#pragma unroll
    for (int w = 0; w < 16; ++w) { s += Xs[w][t]; q += Ws[w][t]; }
    float* dst = st_out + (blockIdx.x & (NBINS - 1)) * 2 * Cout;
    atomicAdd(dst + n0 + t, s);
    atomicAdd(dst + Cout + n0 + t, q);
  }
}

// normalize -> relu -> max over ns rows per group (monotone => max first)
__global__ void bn_apply_relu_maxpool(const float* __restrict__ Y,
                                      const float* __restrict__ st,
                                      float* __restrict__ o, int G, int ns, int C) {
  const int i = blockIdx.x * 256 + threadIdx.x;
  if (i >= G * C) return;
  const int c = i % C;
  const int g = i / C;
  float s = 0.f, q = 0.f;
#pragma unroll
  for (int bn = 0; bn < NBINS; ++bn) {
    s += st[bn * 2 * C + c];
    q += st[bn * 2 * C + C + c];
  }
  const int R = G * ns;
  const float inv = 1.f / (float)R;
  const float m  = s * inv;
  const float vr = fmaf(-m, m, q * inv);
  const float sc = rsqrtf(vr + EPS_BN);
  const float* p = Y + (size_t)g * ns * C + c;
  float mx = -__builtin_inff();
  for (int k = 0; k < ns; ++k) mx = fmaxf(mx, p[(size_t)k * C]);
  o[i] = fmaxf(0.f, (mx - m) * sc);
}

// =====================================================================
// Farthest point sampling — one block per batch, points in registers.
// Bitwise-exact fp32 vs reference.
// amdgpu_waves_per_eu(2,2): pins occupancy target to 2 waves/EU so the
// allocator gets (and uses) a 256-VGPR budget — the 160-float resident
// state must NOT spill (R2/R3 evidence: min-only hint -> 128 VGPRs and
// 1.3 GB scratch traffic per dispatch).
// =====================================================================
template <int N, int NP, int THREADS, int NPT>
__global__ __launch_bounds__(THREADS)
__attribute__((amdgpu_waves_per_eu(2, 2)))
void fps2_kernel(const float* __restrict__ xyz, float* __restrict__ new_xyz) {
  constexpr int NW = THREADS / 64;
  const int b    = blockIdx.x;
  const int tid  = threadIdx.x;
  const int lane = tid & 63;
  const int wave = tid >> 6;
  const float* p = xyz + (size_t)b * N * 3;
  float px[NPT], py[NPT], pz[NPT], dd[NPT];
#pragma unroll
  for (int j = 0; j < NPT; ++j) {
    const int i = tid + j * THREADS;
    if (i < N) {
      px[j] = p[i * 3 + 0];
      py[j] = p[i * 3 + 1];
      pz[j] = p[i * 3 + 2];
      dd[j] = 1e10f;
    } else {
      px[j] = 0.f; py[j] = 0.f; pz[j] = 0.f;
      dd[j] = -__builtin_inff();  // never wins argmax (valid dists >= 0)
    }
  }
  __shared__ float sv[NW], sx[NW], sy[NW], sz[NW];
  __shared__ int   si[NW];
  __shared__ float bc[3];
  float fx = p[0], fy = p[1], fz = p[2];
  if (tid == 0) {
    float* o = new_xyz + (size_t)b * NP * 3;
    o[0] = fx; o[1] = fy; o[2] = fz;
  }
  for (int s = 1; s < NP; ++s) {
    float bv = -__builtin_inff();
    int   bi = 0x7fffffff;
    float bx = 0.f, by = 0.f, bz = 0.f;
#pragma unroll
    for (int j = 0; j < NPT; ++j) {
      const float dx = px[j] - fx;
      const float dy = py[j] - fy;
      const float dz = pz[j] - fz;
      const float d  = __fadd_rn(__fadd_rn(__fmul_rn(dx, dx), __fmul_rn(dy, dy)),
                                 __fmul_rn(dz, dz));
      const float nd = fminf(dd[j], d);
      dd[j] = nd;
      if (nd > bv) { bv = nd; bi = tid + j * THREADS; bx = px[j]; by = py[j]; bz = pz[j]; }
    }
    float v = bv;
    int   i0 = bi;
#pragma unroll
    for (int m = 1; m < 64; m <<= 1) {
      const float ov = __shfl_xor(v, m, 64);
      const int   oi = __shfl_xor(i0, m, 64);
      if (ov > v || (ov == v && oi < i0)) { v = ov; i0 = oi; }
    }
    if (i0 == bi) {  // unique owner lane of this wave's winner
      sv[wave] = bv; si[wave] = bi; sx[wave] = bx; sy[wave] = by; sz[wave] = bz;
    }
    __syncthreads();
    if (tid < 64) {
      const float lv = (lane < NW) ? sv[lane] : -__builtin_inff();
      const int   li = (lane < NW) ? si[lane] : 0x7fffffff;
      float v2 = lv;
      int   i2 = li;
#pragma unroll
      for (int m = 1; m < NW; m <<= 1) {
        const float ov = __shfl_xor(v2, m, 64);
        const int   oi = __shfl_xor(i2, m, 64);
        if (ov > v2 || (ov == v2 && oi < i2)) { v2 = ov; i2 = oi; }
      }
      if (lane < NW && li == i2) {  // unique global owner
        const float wx = sx[lane], wy = sy[lane], wz = sz[lane];
        bc[0] = wx; bc[1] = wy; bc[2] = wz;
        float* o = new_xyz + ((size_t)b * NP + s) * 3;
        o[0] = wx; o[1] = wy; o[2] = wz;
      }
    }
    __syncthreads();
    fx = bc[0]; fy = bc[1]; fz = bc[2];
  }
}

// =====================================================================
// Ball query: first NS points (in index order) with d2 < r2.
// =====================================================================
template <int N, int NS>
__global__ void ballquery_kernel(const float* __restrict__ centers,
                                 const float* __restrict__ pts,
                                 int* __restrict__ idx, int BS, int S, float r2) {
  const int t = blockIdx.x * 256 + threadIdx.x;
  if (t >= BS) return;
  const int b = t / S;
  const float cx = centers[t * 3 + 0];
  const float cy = centers[t * 3 + 1];
  const float cz = centers[t * 3 + 2];
  const float* p = pts + (size_t)b * N * 3;
  int* o = idx + (size_t)t * NS;
  int cnt = 0;
  for (int i0 = 0; i0 < N && cnt < NS; i0 += 16) {
    float xs[16], ys[16], zs[16];
#pragma unroll
    for (int u = 0; u < 16; ++u) {
      xs[u] = p[(i0 + u) * 3 + 0];
      ys[u] = p[(i0 + u) * 3 + 1];
      zs[u] = p[(i0 + u) * 3 + 2];
    }
#pragma unroll
    for (int u = 0; u < 16; ++u) {
      const float dx = cx - xs[u], dy = cy - ys[u], dz = cz - zs[u];
      const float d2 = __fadd_rn(__fadd_rn(__fmul_rn(dx, dx), __fmul_rn(dy, dy)),
                                 __fmul_rn(dz, dz));
      if (d2 < r2 && cnt < NS) { o[cnt] = i0 + u; ++cnt; }
    }
  }
  const int first = o[0];  // center itself guarantees cnt >= 1
  for (int k = cnt; k < NS; ++k) o[k] = first;
}

// =====================================================================
// Grouping / concat kernels
// =====================================================================
__global__ void group1_kernel(const float* __restrict__ xyz, const float* __restrict__ ctr,
                              const int* __restrict__ idx, float* __restrict__ X1) {
  const int t = blockIdx.x * 256 + threadIdx.x;
  if (t >= 8 * 512 * 32) return;
  const int g = t >> 5;   // (b,s)
  const int b = g >> 9;
  const int i = idx[t];
  const float* p = xyz + ((size_t)b * 20000 + i) * 3;
  const float* c = ctr + (size_t)g * 3;
  X1[t * 3 + 0] = (p[0] - c[0]) / 0.2f;
  X1[t * 3 + 1] = (p[1] - c[1]) / 0.2f;
  X1[t * 3 + 2] = (p[2] - c[2]) / 0.2f;
}

__global__ void group2_kernel(const float* __restrict__ xyz1,
                              const float* __restrict__ xyz2,
                              const float* __restrict__ f1,
                              const int* __restrict__ idx2,
                              float* __restrict__ X2) {
  const int t = blockIdx.x * 256 + threadIdx.x;
  if (t >= 65536 * 131) return;
  const int r = t / 131;          // (b,s,k) flattened
  const int c = t - r * 131;
  const int g = r >> 6;           // b*128+s
  const int b = g >> 7;
  const int i = idx2[r];          // idx2[g*64+k] == idx2[r]
  float v;
  if (c < 3) {
    v = (xyz1[((size_t)b * 512 + i) * 3 + c] - xyz2[(size_t)g * 3 + c]) / 0.4f;
  } else {
    v = f1[((size_t)b * 512 + i) * 128 + (c - 3)];
  }
  X2[t] = v;
}

__global__ void build_x3_kernel(const float* __restrict__ xyz2, const float* __restrict__ f2,
                                float* __restrict__ X3) {
  const int t = blockIdx.x * 256 + threadIdx.x;
  if (t >= 1024 * 259) return;
  const int r = t / 259;
  const int c = t - r * 259;
  X3[t] = (c < 3) ? xyz2[r * 3 + c] : f2[(size_t)r * 256 + (c - 3)];
}

// =====================================================================
// Fused head: comb=concat -> BN(batch) -> FC512+BN+relu -> FC256+BN+relu
//             -> FC1 + relu.
// =====================================================================
__global__ __launch_bounds__(512) void head_kernel(
    const float* __restrict__ gfeat, const float* __restrict__ objf,
    const float* __restrict__ w0, const float* __restrict__ b0,
    const float* __restrict__ w1, const float* __restrict__ b1,
    const float* __restrict__ w2, const float* __restrict__ b2,
    float* __restrict__ out) {
  __shared__ float comb[8 * 1152];
  __shared__ float h1[8 * 512];
  __shared__ float h2[8 * 256];
  const int tid = threadIdx.x;
  for (int i = tid; i < 8 * 1152; i += 512) {
    const int b = i / 1152, c = i - b * 1152;
    comb[i] = (c < 128) ? gfeat[b * 128 + c] : objf[b * 1024 + (c - 128)];
  }
  __syncthreads();
  for (int c = tid; c < 1152; c += 512) {
    float s = 0.f;
#pragma unroll
    for (int b = 0; b < 8; ++b) s += comb[b * 1152 + c];
    const float m = s * 0.125f;
    float v = 0.f;
#pragma unroll
    for (int b = 0; b < 8; ++b) { const float d = comb[b * 1152 + c] - m; v = fmaf(d, d, v); }
    const float sc = rsqrtf(v * 0.125f + EPS_BN);
#pragma unroll
    for (int b = 0; b < 8; ++b) comb[b * 1152 + c] = (comb[b * 1152 + c] - m) * sc;
  }
  __syncthreads();
  {  // layer 0: 1152 -> 512
    float a[8];
#pragma unroll
    for (int b = 0; b < 8; ++b) a[b] = b0[tid];
    const float* wr = w0 + (size_t)tid * 1152;
    for (int ci = 0; ci < 1152; ++ci) {
      const float w = wr[ci];
#pragma unroll
      for (int b = 0; b < 8; ++b) a[b] = fmaf(comb[b * 1152 + ci], w, a[b]);
    }
    float s = 0.f;
#pragma unroll
    for (int b = 0; b < 8; ++b) s += a[b];
    const float m = s * 0.125f;
    float v = 0.f;
#pragma unroll
    for (int b = 0; b < 8; ++b) { const float d = a[b] - m; v = fmaf(d, d, v); }
    const float sc = rsqrtf(v * 0.125f + EPS_BN);
#pragma unroll
    for (int b = 0; b < 8; ++b) h1[b * 512 + tid] = fmaxf(0.f, (a[b] - m) * sc);
  }
  __syncthreads();
  if (tid < 256) {  // layer 1: 512 -> 256
    float a[8];
#pragma unroll
    for (int b = 0; b < 8; ++b) a[b] = b1[tid];
    const float* wr = w1 + (size_t)tid * 512;
    for (int ci = 0; ci < 512; ++ci) {
      const float w = wr[ci];
#pragma unroll
      for (int b = 0; b < 8; ++b) a[b] = fmaf(h1[b * 512 + ci], w, a[b]);
    }
    float s = 0.f;
#pragma unroll
    for (int b = 0; b < 8; ++b) s += a[b];
    const float m = s * 0.125f;
    float v = 0.f;
#pragma unroll
    for (int b = 0; b < 8; ++b) { const float d = a[b] - m; v = fmaf(d, d, v); }
    const float sc = rsqrtf(v * 0.125f + EPS_BN);
#pragma unroll
    for (int b = 0; b < 8; ++b) h2[b * 256 + tid] = fmaxf(0.f, (a[b] - m) * sc);
  }
  __syncthreads();
  if (tid < 8) {  // layer 2: 256 -> 1, relu
    float s = b2[0];
    for (int ci = 0; ci < 256; ++ci) s = fmaf(h2[tid * 256 + ci], w2[ci], s);
    out[tid] = fmaxf(0.f, s);
  }
}

// =====================================================================
// Host orchestration
// =====================================================================
extern "C" void kernel_launch(void* const* d_in, const int* in_sizes, int n_in,
                              void* d_out, int out_size, void* d_ws, size_t ws_size,
                              hipStream_t stream) {
  (void)in_sizes; (void)n_in; (void)out_size; (void)ws_size;
  const float* obj  = (const float*)d_in[0];
  const float* grip = (const float*)d_in[1];
  const float* s1w0 = (const float*)d_in[2];
  const float* s1w1 = (const float*)d_in[3];
  const float* s1w2 = (const float*)d_in[4];
  const float* s2w0 = (const float*)d_in[5];
  const float* s2w1 = (const float*)d_in[6];
  const float* s2w2 = (const float*)d_in[7];
  const float* s3w0 = (const float*)d_in[8];
  const float* s3w1 = (const float*)d_in[9];
  const float* s3w2 = (const float*)d_in[10];
  const float* gw0  = (const float*)d_in[11];
  const float* gw1  = (const float*)d_in[12];
  const float* gw2  = (const float*)d_in[13];
  const float* hw0  = (const float*)d_in[14];
  const float* hb0  = (const float*)d_in[15];
  const float* hw1  = (const float*)d_in[16];
  const float* hb1  = (const float*)d_in[17];
  const float* hw2  = (const float*)d_in[18];
  const float* hb2  = (const float*)d_in[19];
  float* out = (float*)d_out;

  // ---- workspace layout (float offsets); total 26,658,304 floats ----
  float* wsf   = (float*)d_ws;
  float* stats = wsf;                    // 12 layers, 4 bins x 2C each = 23040
  float* xyz1  = wsf + 23040;            // 8*512*3
  float* xyz2  = wsf + 35328;            // 8*128*3
  float* gfeat = wsf + 38400;            // 8*128
  float* objf  = wsf + 39424;            // 8*1024
  float* f1    = wsf + 47616;            // 4096*128
  float* f2    = wsf + 571904;           // 1024*256
  float* x3    = wsf + 834048;           // 1024*259
  int*   idx1  = (int*)(wsf + 1099264);  // 8*512*32
  int*   idx2  = (int*)(wsf + 1230336);  // 8*128*64
  float* bufP  = wsf + 1295872;          // 16,777,216 floats
  float* bufQ  = wsf + 18073088;         // 8,585,216 floats

  // per-layer stats offsets (4 bins x 2C, cumulative)
  static const int st_off[12] = {0, 512, 1536, 2560, 3072, 3584,
                                 4608, 5632, 6656, 8704, 10752, 14848};
  auto st = [&](int li) { return stats + st_off[li]; };

  hipMemsetAsync(stats, 0, 23040 * sizeof(float), stream);

  auto gemm0 = [&](const float* X, const float* Wm, float* Y, int R, int Cin, int Cout,
                   int lo) {  // raw input
    dim3 g((R + 63) / 64, (Cout + 63) / 64);
    gemm_xwt<false><<<g, 256, 0, stream>>>(X, Wm, Y, R, Cin, Cout, nullptr, 0, st(lo));
  };
  auto gemmf = [&](const float* X, const float* Wm, float* Y, int R, int Cin, int Cout,
                   int li, int lo) {  // BN(li)+relu fused on X
    dim3 g((R + 63) / 64, (Cout + 63) / 64);
    gemm_xwt<true><<<g, 256, 0, stream>>>(X, Wm, Y, R, Cin, Cout, st(li), R, st(lo));
  };
  auto applymax_k = [&](const float* Y, int li, int G, int ns, int C, float* o) {
    const int n = G * C;
    bn_apply_relu_maxpool<<<(n + 255) / 256, 256, 0, stream>>>(Y, st(li), o, G, ns, C);
  };

  // ---- gripper encoder: [8,512,3] -> 64 -> 128 -> 128 -> maxpool ----
  float* gY1 = bufP;
  float* gY2 = bufP + 262144;
  float* gY3 = bufP + 786432;
  gemm0(grip, gw0, gY1, 4096, 3, 64, 0);
  gemmf(gY1, gw1, gY2, 4096, 64, 128, 0, 1);
  gemmf(gY2, gw2, gY3, 4096, 128, 128, 1, 2);
  applymax_k(gY3, 2, 8, 512, 128, gfeat);

  // ---- SA1: FPS 20000->512, ball r=0.2 ns=32, MLP 3->64->64->128 ----
  fps2_kernel<20000, 512, 512, 40><<<8, 512, 0, stream>>>(obj, xyz1);
  ballquery_kernel<20000, 32><<<16, 256, 0, stream>>>(xyz1, obj, idx1, 4096, 512, 0.04f);
  float* X1 = bufQ;
  group1_kernel<<<512, 256, 0, stream>>>(obj, xyz1, idx1, X1);
  gemm0(X1, s1w0, bufP, 131072, 3, 64, 3);
  gemmf(bufP, s1w1, bufQ, 131072, 64, 64, 3, 4);
  gemmf(bufQ, s1w2, bufP, 131072, 64, 128, 4, 5);
  applymax_k(bufP, 5, 4096, 32, 128, f1);

  // ---- SA2: FPS 512->128, ball r=0.4 ns=64, MLP 131->128->128->256 ----
  fps2_kernel<512, 128, 256, 2><<<8, 256, 0, stream>>>(xyz1, xyz2);
  ballquery_kernel<512, 64><<<4, 256, 0, stream>>>(xyz2, xyz1, idx2, 1024, 128, 0.16f);
  float* X2 = bufQ;
  group2_kernel<<<(65536 * 131 + 255) / 256, 256, 0, stream>>>(xyz1, xyz2, f1, idx2, X2);
  gemm0(X2, s2w0, bufP, 65536, 131, 128, 6);
  gemmf(bufP, s2w1, bufQ, 65536, 128, 128, 6, 7);
  gemmf(bufQ, s2w2, bufP, 65536, 128, 256, 7, 8);
  applymax_k(bufP, 8, 1024, 64, 256, f2);

  // ---- SA3 (group_all): concat[xyz2,f2] -> 256 -> 512 -> 1024 -> maxpool ----
  build_x3_kernel<<<(1024 * 259 + 255) / 256, 256, 0, stream>>>(xyz2, f2, x3);
  float* Y3a = bufQ;
  float* Y3b = bufQ + 262144;
  float* Y3c = bufQ + 786432;
  gemm0(x3, s3w0, Y3a, 1024, 259, 256, 9);
  gemmf(Y3a, s3w1, Y3b, 1024, 256, 512, 9, 10);
  gemmf(Y3b, s3w2, Y3c, 1024, 512, 1024, 10, 11);
  applymax_k(Y3c, 11, 8, 128, 1024, objf);

  // ---- head ----
  head_kernel<<<1, 512, 0, stream>>>(gfeat, objf, hw0, hb0, hw1, hb1, hw2, hb2, out);
}

// Round 5
// 2929.127 us; speedup vs baseline: 1.1391x; 1.1391x over previous
//
#include <hip/hip_runtime.h>
#include <cstddef>
#include <cstdint>

#define EPS_BN 1e-5f
#define NBINS 4

// =====================================================================
// Tiled fp32 GEMM:  Y[r][o] = sum_ci X'[r][ci] * W[o][ci]   (Y = X' W^T)
// 64x64 tile, BK=16, 256 threads, 4x4 microtile/thread.
// FUSE_IN: X' = relu((X - mean)*scale) from st_in bins (prev layer BN).
// Epilogue: per-column sum / sumsq of raw Y accumulated into st_out bins.
// =====================================================================
template <bool FUSE_IN>
__global__ __launch_bounds__(256) void gemm_xwt(const float* __restrict__ X,
                                                const float* __restrict__ Wm,
                                                float* __restrict__ Y,
                                                int R, int Cin, int Cout,
                                                const float* __restrict__ st_in, int Rin,
                                                float* __restrict__ st_out) {
  __shared__ __align__(16) float Xs[16][68];   // [k][m], pad 68 -> conflict-free
  __shared__ __align__(16) float Ws[16][68];   // [k][n]
  __shared__ float sMean[512], sScale[512];    // only used when FUSE_IN
  const int t  = threadIdx.x;
  const int r0 = blockIdx.x << 6;
  const int n0 = blockIdx.y << 6;
  const int lk = t & 15;
  const int lm = t >> 4;
  const int tx = t & 15;
  const int ty = t >> 4;

  if constexpr (FUSE_IN) {
    const float inv = 1.f / (float)Rin;
    for (int k = t; k < Cin; k += 256) {
      float s = 0.f, q = 0.f;
#pragma unroll
      for (int bn = 0; bn < NBINS; ++bn) {
        s += st_in[bn * 2 * Cin + k];
        q += st_in[bn * 2 * Cin + Cin + k];
      }
      const float m  = s * inv;
      const float vr = fmaf(-m, m, q * inv);
      sMean[k]  = m;
      sScale[k] = rsqrtf(vr + EPS_BN);
    }
    __syncthreads();
  }

  float acc[4][4] = {{0.f, 0.f, 0.f, 0.f}, {0.f, 0.f, 0.f, 0.f},
                     {0.f, 0.f, 0.f, 0.f}, {0.f, 0.f, 0.f, 0.f}};
  for (int k0 = 0; k0 < Cin; k0 += 16) {
    const int k  = k0 + lk;
    const bool kv = (k < Cin);
#pragma unroll
    for (int q = 0; q < 4; ++q) {
      const int m = lm + (q << 4);
      const int r = r0 + m;
      float xv = (kv && r < R) ? X[(size_t)r * Cin + k] : 0.f;
      if constexpr (FUSE_IN) {
        if (kv && r < R) xv = fmaxf(0.f, (xv - sMean[k]) * sScale[k]);
      }
      Xs[lk][m] = xv;
      const int n = n0 + m;
      Ws[lk][m] = (kv && n < Cout) ? Wm[(size_t)n * Cin + k] : 0.f;
    }
    __syncthreads();
#pragma unroll
    for (int kk = 0; kk < 16; ++kk) {
      const float4 a = *(const float4*)(&Xs[kk][ty << 2]);
      const float4 b = *(const float4*)(&Ws[kk][tx << 2]);
      acc[0][0] = fmaf(a.x, b.x, acc[0][0]);
      acc[0][1] = fmaf(a.x, b.y, acc[0][1]);
      acc[0][2] = fmaf(a.x, b.z, acc[0][2]);
      acc[0][3] = fmaf(a.x, b.w, acc[0][3]);
      acc[1][0] = fmaf(a.y, b.x, acc[1][0]);
      acc[1][1] = fmaf(a.y, b.y, acc[1][1]);
      acc[1][2] = fmaf(a.y, b.z, acc[1][2]);
      acc[1][3] = fmaf(a.y, b.w, acc[1][3]);
      acc[2][0] = fmaf(a.z, b.x, acc[2][0]);
      acc[2][1] = fmaf(a.z, b.y, acc[2][1]);
      acc[2][2] = fmaf(a.z, b.z, acc[2][2]);
      acc[2][3] = fmaf(a.z, b.w, acc[2][3]);
      acc[3][0] = fmaf(a.w, b.x, acc[3][0]);
      acc[3][1] = fmaf(a.w, b.y, acc[3][1]);
      acc[3][2] = fmaf(a.w, b.z, acc[3][2]);
      acc[3][3] = fmaf(a.w, b.w, acc[3][3]);
    }
    __syncthreads();
  }
  // store Y
#pragma unroll
  for (int i = 0; i < 4; ++i) {
    const int r = r0 + (ty << 2) + i;
    if (r < R) {
#pragma unroll
      for (int j = 0; j < 4; ++j) {
        const int n = n0 + (tx << 2) + j;
        if (n < Cout) Y[(size_t)r * Cout + n] = acc[i][j];
      }
    }
  }
  // epilogue: per-column partials -> LDS reduce -> binned atomics
  float4 sj, qj;
  {
    float s, q;
#define COLP(J, FLD)                                                        \
    s = acc[0][J] + acc[1][J] + acc[2][J] + acc[3][J];                      \
    q = acc[0][J] * acc[0][J];                                              \
    q = fmaf(acc[1][J], acc[1][J], q);                                      \
    q = fmaf(acc[2][J], acc[2][J], q);                                      \
    q = fmaf(acc[3][J], acc[3][J], q);                                      \
    sj.FLD = s; qj.FLD = q;
    COLP(0, x) COLP(1, y) COLP(2, z) COLP(3, w)
#undef COLP
  }
  *(float4*)(&Xs[ty][tx << 2]) = sj;
  *(float4*)(&Ws[ty][tx << 2]) = qj;
  __syncthreads();
  if (t < 64) {
    float s = 0.f, q = 0.f;
#pragma unroll
    for (int w = 0; w < 16; ++w) { s += Xs[w][t]; q += Ws[w][t]; }
    float* dst = st_out + (blockIdx.x & (NBINS - 1)) * 2 * Cout;
    atomicAdd(dst + n0 + t, s);
    atomicAdd(dst + Cout + n0 + t, q);
  }
}

// normalize -> relu -> max over ns rows per group (monotone => max first)
__global__ void bn_apply_relu_maxpool(const float* __restrict__ Y,
                                      const float* __restrict__ st,
                                      float* __restrict__ o, int G, int ns, int C) {
  const int i = blockIdx.x * 256 + threadIdx.x;
  if (i >= G * C) return;
  const int c = i % C;
  const int g = i / C;
  float s = 0.f, q = 0.f;
#pragma unroll
  for (int bn = 0; bn < NBINS; ++bn) {
    s += st[bn * 2 * C + c];
    q += st[bn * 2 * C + C + c];
  }
  const int R = G * ns;
  const float inv = 1.f / (float)R;
  const float m  = s * inv;
  const float vr = fmaf(-m, m, q * inv);
  const float sc = rsqrtf(vr + EPS_BN);
  const float* p = Y + (size_t)g * ns * C + c;
  float mx = -__builtin_inff();
  for (int k = 0; k < ns; ++k) mx = fmaxf(mx, p[(size_t)k * C]);
  o[i] = fmaxf(0.f, (mx - m) * sc);
}

// =====================================================================
// FPS for SA1 (N=20000 -> 512), one block of 1024 threads per batch.
// Register-pressure-proof design (R1-R4 evidence: allocator picks 64 or
// 128 VGPRs regardless of hints and spills anything bigger to scratch,
// 1.3 GB/dispatch):
//   k=0..11 : coords STREAMED from global (L2-resident), dd in LDS 48KB
//   k=12..19: coords + dd in macro-scalarized REGISTERS (32 regs)
// -> ~52 live VGPRs, fits even a 64-VGPR allocation. Bitwise-exact math
// (no FMA contraction, exact fp32 min, first-index tie-break).
// =====================================================================
#define REPA(X) X(0) X(1) X(2) X(3) X(4) X(5) X(6) X(7) X(8) X(9) X(10) X(11)
#define REPB(X) X(12) X(13) X(14) X(15) X(16) X(17) X(18) X(19)

__global__ __launch_bounds__(1024)
void fps_sa1_kernel(const float* __restrict__ xyz, float* __restrict__ new_xyz) {
  const int b    = blockIdx.x;
  const int tid  = threadIdx.x;
  const int lane = tid & 63;
  const int wave = tid >> 6;  // 0..15
  const float* p = xyz + (size_t)b * 20000 * 3;

  __shared__ float ddL[12 * 1024];  // 48 KB; bank = tid%32 -> free 2-way
  __shared__ float sv[16], sx[16], sy[16], sz[16];
  __shared__ int   si[16];
  __shared__ float bc[3];

  // registers for k=12..19
#define DECLR(k) float px##k, py##k, pz##k, dd##k;
  REPB(DECLR)
#undef DECLR

  // init LDS dd (k=0..11: i = tid + k*1024 <= 13311 < 20000, always valid)
#define INITL(k) ddL[(k) * 1024 + tid] = 1e10f;
  REPA(INITL)
#undef INITL
  // init register points (only k=19 can run past N=20000)
#define INITR(k) {                                                          \
    const int i = tid + (k) * 1024;                                         \
    if (i < 20000) {                                                        \
      px##k = p[i * 3 + 0]; py##k = p[i * 3 + 1]; pz##k = p[i * 3 + 2];     \
      dd##k = 1e10f;                                                        \
    } else {                                                                \
      px##k = 0.f; py##k = 0.f; pz##k = 0.f;                                \
      dd##k = -__builtin_inff();                                            \
    } }
  REPB(INITR)
#undef INITR

  float fx = p[0], fy = p[1], fz = p[2];
  if (tid == 0) {
    float* o = new_xyz + (size_t)b * 512 * 3;
    o[0] = fx; o[1] = fy; o[2] = fz;
  }
  __syncthreads();

  for (int s = 1; s < 512; ++s) {
    float bv = -__builtin_inff();
    int   bi = 0x7fffffff;
    float bx = 0.f, by = 0.f, bz = 0.f;
    // streamed region (ascending index order for first-index tie-break)
#define SCANS(k) {                                                          \
    const int i = tid + (k) * 1024;                                         \
    const float qx = p[i * 3 + 0], qy = p[i * 3 + 1], qz = p[i * 3 + 2];    \
    const float dx = qx - fx, dy = qy - fy, dz = qz - fz;                   \
    const float d  = __fadd_rn(__fadd_rn(__fmul_rn(dx, dx), __fmul_rn(dy, dy)), \
                               __fmul_rn(dz, dz));                          \
    const float nd = fminf(ddL[(k) * 1024 + tid], d);                       \
    ddL[(k) * 1024 + tid] = nd;                                             \
    if (nd > bv) { bv = nd; bi = i; bx = qx; by = qy; bz = qz; } }
    REPA(SCANS)
#undef SCANS
    // register region
#define SCANR(k) {                                                          \
    const float dx = px##k - fx, dy = py##k - fy, dz = pz##k - fz;          \
    const float d  = __fadd_rn(__fadd_rn(__fmul_rn(dx, dx), __fmul_rn(dy, dy)), \
                               __fmul_rn(dz, dz));                          \
    const float nd = fminf(dd##k, d);                                       \
    dd##k = nd;                                                             \
    if (nd > bv) { bv = nd; bi = tid + (k) * 1024;                          \
                   bx = px##k; by = py##k; bz = pz##k; } }
    REPB(SCANR)
#undef SCANR
    // wave butterfly on (value, index); originals kept for owner detection
    float v  = bv;
    int   i0 = bi;
#pragma unroll
    for (int m = 1; m < 64; m <<= 1) {
      const float ov = __shfl_xor(v, m, 64);
      const int   oi = __shfl_xor(i0, m, 64);
      if (ov > v || (ov == v && oi < i0)) { v = ov; i0 = oi; }
    }
    if (i0 == bi) {  // unique owner lane of this wave's winner
      sv[wave] = bv; si[wave] = bi; sx[wave] = bx; sy[wave] = by; sz[wave] = bz;
    }
    __syncthreads();
    if (tid < 64) {
      const float lv = (lane < 16) ? sv[lane] : -__builtin_inff();
      const int   li = (lane < 16) ? si[lane] : 0x7fffffff;
      float v2 = lv;
      int   i2 = li;
#pragma unroll
      for (int m = 1; m < 16; m <<= 1) {
        const float ov = __shfl_xor(v2, m, 64);
        const int   oi = __shfl_xor(i2, m, 64);
        if (ov > v2 || (ov == v2 && oi < i2)) { v2 = ov; i2 = oi; }
      }
      if (lane < 16 && li == i2) {  // unique global owner
        const float wx = sx[lane], wy = sy[lane], wz = sz[lane];
        bc[0] = wx; bc[1] = wy; bc[2] = wz;
        float* o = new_xyz + ((size_t)b * 512 + s) * 3;
        o[0] = wx; o[1] = wy; o[2] = wz;
      }
    }
    __syncthreads();
    fx = bc[0]; fy = bc[1]; fz = bc[2];
  }
}

// =====================================================================
// FPS small (SA2: 512 -> 128), one block per batch, all state in regs.
// =====================================================================
template <int N, int NP, int THREADS, int NPT>
__global__ __launch_bounds__(THREADS)
void fps2_kernel(const float* __restrict__ xyz, float* __restrict__ new_xyz) {
  constexpr int NW = THREADS / 64;
  const int b    = blockIdx.x;
  const int tid  = threadIdx.x;
  const int lane = tid & 63;
  const int wave = tid >> 6;
  const float* p = xyz + (size_t)b * N * 3;
  float px[NPT], py[NPT], pz[NPT], dd[NPT];
#pragma unroll
  for (int j = 0; j < NPT; ++j) {
    const int i = tid + j * THREADS;
    if (i < N) {
      px[j] = p[i * 3 + 0];
      py[j] = p[i * 3 + 1];
      pz[j] = p[i * 3 + 2];
      dd[j] = 1e10f;
    } else {
      px[j] = 0.f; py[j] = 0.f; pz[j] = 0.f;
      dd[j] = -__builtin_inff();
    }
  }
  __shared__ float sv[NW], sx[NW], sy[NW], sz[NW];
  __shared__ int   si[NW];
  __shared__ float bc[3];
  float fx = p[0], fy = p[1], fz = p[2];
  if (tid == 0) {
    float* o = new_xyz + (size_t)b * NP * 3;
    o[0] = fx; o[1] = fy; o[2] = fz;
  }
  for (int s = 1; s < NP; ++s) {
    float bv = -__builtin_inff();
    int   bi = 0x7fffffff;
    float bx = 0.f, by = 0.f, bz = 0.f;
#pragma unroll
    for (int j = 0; j < NPT; ++j) {
      const float dx = px[j] - fx;
      const float dy = py[j] - fy;
      const float dz = pz[j] - fz;
      const float d  = __fadd_rn(__fadd_rn(__fmul_rn(dx, dx), __fmul_rn(dy, dy)),
                                 __fmul_rn(dz, dz));
      const float nd = fminf(dd[j], d);
      dd[j] = nd;
      if (nd > bv) { bv = nd; bi = tid + j * THREADS; bx = px[j]; by = py[j]; bz = pz[j]; }
    }
    float v = bv;
    int   i0 = bi;
#pragma unroll
    for (int m = 1; m < 64; m <<= 1) {
      const float ov = __shfl_xor(v, m, 64);
      const int   oi = __shfl_xor(i0, m, 64);
      if (ov > v || (ov == v && oi < i0)) { v = ov; i0 = oi; }
    }
    if (i0 == bi) {
      sv[wave] = bv; si[wave] = bi; sx[wave] = bx; sy[wave] = by; sz[wave] = bz;
    }
    __syncthreads();
    if (tid < 64) {
      const float lv = (lane < NW) ? sv[lane] : -__builtin_inff();
      const int   li = (lane < NW) ? si[lane] : 0x7fffffff;
      float v2 = lv;
      int   i2 = li;
#pragma unroll
      for (int m = 1; m < NW; m <<= 1) {
        const float ov = __shfl_xor(v2, m, 64);
        const int   oi = __shfl_xor(i2, m, 64);
        if (ov > v2 || (ov == v2 && oi < i2)) { v2 = ov; i2 = oi; }
      }
      if (lane < NW && li == i2) {
        const float wx = sx[lane], wy = sy[lane], wz = sz[lane];
        bc[0] = wx; bc[1] = wy; bc[2] = wz;
        float* o = new_xyz + ((size_t)b * NP + s) * 3;
        o[0] = wx; o[1] = wy; o[2] = wz;
      }
    }
    __syncthreads();
    fx = bc[0]; fy = bc[1]; fz = bc[2];
  }
}

// =====================================================================
// Ball query: first NS points (in index order) with d2 < r2.
// =====================================================================
template <int N, int NS>
__global__ void ballquery_kernel(const float* __restrict__ centers,
                                 const float* __restrict__ pts,
                                 int* __restrict__ idx, int BS, int S, float r2) {
  const int t = blockIdx.x * 256 + threadIdx.x;
  if (t >= BS) return;
  const int b = t / S;
  const float cx = centers[t * 3 + 0];
  const float cy = centers[t * 3 + 1];
  const float cz = centers[t * 3 + 2];
  const float* p = pts + (size_t)b * N * 3;
  int* o = idx + (size_t)t * NS;
  int cnt = 0;
  for (int i0 = 0; i0 < N && cnt < NS; i0 += 16) {
    float xs[16], ys[16], zs[16];
#pragma unroll
    for (int u = 0; u < 16; ++u) {
      xs[u] = p[(i0 + u) * 3 + 0];
      ys[u] = p[(i0 + u) * 3 + 1];
      zs[u] = p[(i0 + u) * 3 + 2];
    }
#pragma unroll
    for (int u = 0; u < 16; ++u) {
      const float dx = cx - xs[u], dy = cy - ys[u], dz = cz - zs[u];
      const float d2 = __fadd_rn(__fadd_rn(__fmul_rn(dx, dx), __fmul_rn(dy, dy)),
                                 __fmul_rn(dz, dz));
      if (d2 < r2 && cnt < NS) { o[cnt] = i0 + u; ++cnt; }
    }
  }
  const int first = o[0];  // center itself guarantees cnt >= 1
  for (int k = cnt; k < NS; ++k) o[k] = first;
}

// =====================================================================
// Grouping / concat kernels
// =====================================================================
__global__ void group1_kernel(const float* __restrict__ xyz, const float* __restrict__ ctr,
                              const int* __restrict__ idx, float* __restrict__ X1) {
  const int t = blockIdx.x * 256 + threadIdx.x;
  if (t >= 8 * 512 * 32) return;
  const int g = t >> 5;   // (b,s)
  const int b = g >> 9;
  const int i = idx[t];
  const float* p = xyz + ((size_t)b * 20000 + i) * 3;
  const float* c = ctr + (size_t)g * 3;
  X1[t * 3 + 0] = (p[0] - c[0]) / 0.2f;
  X1[t * 3 + 1] = (p[1] - c[1]) / 0.2f;
  X1[t * 3 + 2] = (p[2] - c[2]) / 0.2f;
}

__global__ void group2_kernel(const float* __restrict__ xyz1,
                              const float* __restrict__ xyz2,
                              const float* __restrict__ f1,
                              const int* __restrict__ idx2,
                              float* __restrict__ X2) {
  const int t = blockIdx.x * 256 + threadIdx.x;
  if (t >= 65536 * 131) return;
  const int r = t / 131;          // (b,s,k) flattened
  const int c = t - r * 131;
  const int g = r >> 6;           // b*128+s
  const int b = g >> 7;
  const int i = idx2[r];
  float v;
  if (c < 3) {
    v = (xyz1[((size_t)b * 512 + i) * 3 + c] - xyz2[(size_t)g * 3 + c]) / 0.4f;
  } else {
    v = f1[((size_t)b * 512 + i) * 128 + (c - 3)];
  }
  X2[t] = v;
}

__global__ void build_x3_kernel(const float* __restrict__ xyz2, const float* __restrict__ f2,
                                float* __restrict__ X3) {
  const int t = blockIdx.x * 256 + threadIdx.x;
  if (t >= 1024 * 259) return;
  const int r = t / 259;
  const int c = t - r * 259;
  X3[t] = (c < 3) ? xyz2[r * 3 + c] : f2[(size_t)r * 256 + (c - 3)];
}

// =====================================================================
// Fused head: comb=concat -> BN(batch) -> FC512+BN+relu -> FC256+BN+relu
//             -> FC1 + relu.
// =====================================================================
__global__ __launch_bounds__(512) void head_kernel(
    const float* __restrict__ gfeat, const float* __restrict__ objf,
    const float* __restrict__ w0, const float* __restrict__ b0,
    const float* __restrict__ w1, const float* __restrict__ b1,
    const float* __restrict__ w2, const float* __restrict__ b2,
    float* __restrict__ out) {
  __shared__ float comb[8 * 1152];
  __shared__ float h1[8 * 512];
  __shared__ float h2[8 * 256];
  const int tid = threadIdx.x;
  for (int i = tid; i < 8 * 1152; i += 512) {
    const int b = i / 1152, c = i - b * 1152;
    comb[i] = (c < 128) ? gfeat[b * 128 + c] : objf[b * 1024 + (c - 128)];
  }
  __syncthreads();
  for (int c = tid; c < 1152; c += 512) {
    float s = 0.f;
#pragma unroll
    for (int b = 0; b < 8; ++b) s += comb[b * 1152 + c];
    const float m = s * 0.125f;
    float v = 0.f;
#pragma unroll
    for (int b = 0; b < 8; ++b) { const float d = comb[b * 1152 + c] - m; v = fmaf(d, d, v); }
    const float sc = rsqrtf(v * 0.125f + EPS_BN);
#pragma unroll
    for (int b = 0; b < 8; ++b) comb[b * 1152 + c] = (comb[b * 1152 + c] - m) * sc;
  }
  __syncthreads();
  {  // layer 0: 1152 -> 512
    float a[8];
#pragma unroll
    for (int b = 0; b < 8; ++b) a[b] = b0[tid];
    const float* wr = w0 + (size_t)tid * 1152;
    for (int ci = 0; ci < 1152; ++ci) {
      const float w = wr[ci];
#pragma unroll
      for (int b = 0; b < 8; ++b) a[b] = fmaf(comb[b * 1152 + ci], w, a[b]);
    }
    float s = 0.f;
#pragma unroll
    for (int b = 0; b < 8; ++b) s += a[b];
    const float m = s * 0.125f;
    float v = 0.f;
#pragma unroll
    for (int b = 0; b < 8; ++b) { const float d = a[b] - m; v = fmaf(d, d, v); }
    const float sc = rsqrtf(v * 0.125f + EPS_BN);
#pragma unroll
    for (int b = 0; b < 8; ++b) h1[b * 512 + tid] = fmaxf(0.f, (a[b] - m) * sc);
  }
  __syncthreads();
  if (tid < 256) {  // layer 1: 512 -> 256
    float a[8];
#pragma unroll
    for (int b = 0; b < 8; ++b) a[b] = b1[tid];
    const float* wr = w1 + (size_t)tid * 512;
    for (int ci = 0; ci < 512; ++ci) {
      const float w = wr[ci];
#pragma unroll
      for (int b = 0; b < 8; ++b) a[b] = fmaf(h1[b * 512 + ci], w, a[b]);
    }
    float s = 0.f;
#pragma unroll
    for (int b = 0; b < 8; ++b) s += a[b];
    const float m = s * 0.125f;
    float v = 0.f;
#pragma unroll
    for (int b = 0; b < 8; ++b) { const float d = a[b] - m; v = fmaf(d, d, v); }
    const float sc = rsqrtf(v * 0.125f + EPS_BN);
#pragma unroll
    for (int b = 0; b < 8; ++b) h2[b * 256 + tid] = fmaxf(0.f, (a[b] - m) * sc);
  }
  __syncthreads();
  if (tid < 8) {  // layer 2: 256 -> 1, relu
    float s = b2[0];
    for (int ci = 0; ci < 256; ++ci) s = fmaf(h2[tid * 256 + ci], w2[ci], s);
    out[tid] = fmaxf(0.f, s);
  }
}

// =====================================================================
// Host orchestration
// =====================================================================
extern "C" void kernel_launch(void* const* d_in, const int* in_sizes, int n_in,
                              void* d_out, int out_size, void* d_ws, size_t ws_size,
                              hipStream_t stream) {
  (void)in_sizes; (void)n_in; (void)out_size; (void)ws_size;
  const float* obj  = (const float*)d_in[0];
  const float* grip = (const float*)d_in[1];
  const float* s1w0 = (const float*)d_in[2];
  const float* s1w1 = (const float*)d_in[3];
  const float* s1w2 = (const float*)d_in[4];
  const float* s2w0 = (const float*)d_in[5];
  const float* s2w1 = (const float*)d_in[6];
  const float* s2w2 = (const float*)d_in[7];
  const float* s3w0 = (const float*)d_in[8];
  const float* s3w1 = (const float*)d_in[9];
  const float* s3w2 = (const float*)d_in[10];
  const float* gw0  = (const float*)d_in[11];
  const float* gw1  = (const float*)d_in[12];
  const float* gw2  = (const float*)d_in[13];
  const float* hw0  = (const float*)d_in[14];
  const float* hb0  = (const float*)d_in[15];
  const float* hw1  = (const float*)d_in[16];
  const float* hb1  = (const float*)d_in[17];
  const float* hw2  = (const float*)d_in[18];
  const float* hb2  = (const float*)d_in[19];
  float* out = (float*)d_out;

  // ---- workspace layout (float offsets); total 26,658,304 floats ----
  float* wsf   = (float*)d_ws;
  float* stats = wsf;                    // 12 layers, 4 bins x 2C each = 23040
  float* xyz1  = wsf + 23040;            // 8*512*3
  float* xyz2  = wsf + 35328;            // 8*128*3
  float* gfeat = wsf + 38400;            // 8*128
  float* objf  = wsf + 39424;            // 8*1024
  float* f1    = wsf + 47616;            // 4096*128
  float* f2    = wsf + 571904;           // 1024*256
  float* x3    = wsf + 834048;           // 1024*259
  int*   idx1  = (int*)(wsf + 1099264);  // 8*512*32
  int*   idx2  = (int*)(wsf + 1230336);  // 8*128*64
  float* bufP  = wsf + 1295872;          // 16,777,216 floats
  float* bufQ  = wsf + 18073088;         // 8,585,216 floats

  // per-layer stats offsets (4 bins x 2C, cumulative)
  static const int st_off[12] = {0, 512, 1536, 2560, 3072, 3584,
                                 4608, 5632, 6656, 8704, 10752, 14848};
  auto st = [&](int li) { return stats + st_off[li]; };

  hipMemsetAsync(stats, 0, 23040 * sizeof(float), stream);

  auto gemm0 = [&](const float* X, const float* Wm, float* Y, int R, int Cin, int Cout,
                   int lo) {  // raw input
    dim3 g((R + 63) / 64, (Cout + 63) / 64);
    gemm_xwt<false><<<g, 256, 0, stream>>>(X, Wm, Y, R, Cin, Cout, nullptr, 0, st(lo));
  };
  auto gemmf = [&](const float* X, const float* Wm, float* Y, int R, int Cin, int Cout,
                   int li, int lo) {  // BN(li)+relu fused on X
    dim3 g((R + 63) / 64, (Cout + 63) / 64);
    gemm_xwt<true><<<g, 256, 0, stream>>>(X, Wm, Y, R, Cin, Cout, st(li), R, st(lo));
  };
  auto applymax_k = [&](const float* Y, int li, int G, int ns, int C, float* o) {
    const int n = G * C;
    bn_apply_relu_maxpool<<<(n + 255) / 256, 256, 0, stream>>>(Y, st(li), o, G, ns, C);
  };

  // ---- gripper encoder: [8,512,3] -> 64 -> 128 -> 128 -> maxpool ----
  float* gY1 = bufP;
  float* gY2 = bufP + 262144;
  float* gY3 = bufP + 786432;
  gemm0(grip, gw0, gY1, 4096, 3, 64, 0);
  gemmf(gY1, gw1, gY2, 4096, 64, 128, 0, 1);
  gemmf(gY2, gw2, gY3, 4096, 128, 128, 1, 2);
  applymax_k(gY3, 2, 8, 512, 128, gfeat);

  // ---- SA1: FPS 20000->512, ball r=0.2 ns=32, MLP 3->64->64->128 ----
  fps_sa1_kernel<<<8, 1024, 0, stream>>>(obj, xyz1);
  ballquery_kernel<20000, 32><<<16, 256, 0, stream>>>(xyz1, obj, idx1, 4096, 512, 0.04f);
  float* X1 = bufQ;
  group1_kernel<<<512, 256, 0, stream>>>(obj, xyz1, idx1, X1);
  gemm0(X1, s1w0, bufP, 131072, 3, 64, 3);
  gemmf(bufP, s1w1, bufQ, 131072, 64, 64, 3, 4);
  gemmf(bufQ, s1w2, bufP, 131072, 64, 128, 4, 5);
  applymax_k(bufP, 5, 4096, 32, 128, f1);

  // ---- SA2: FPS 512->128, ball r=0.4 ns=64, MLP 131->128->128->256 ----
  fps2_kernel<512, 128, 256, 2><<<8, 256, 0, stream>>>(xyz1, xyz2);
  ballquery_kernel<512, 64><<<4, 256, 0, stream>>>(xyz2, xyz1, idx2, 1024, 128, 0.16f);
  float* X2 = bufQ;
  group2_kernel<<<(65536 * 131 + 255) / 256, 256, 0, stream>>>(xyz1, xyz2, f1, idx2, X2);
  gemm0(X2, s2w0, bufP, 65536, 131, 128, 6);
  gemmf(bufP, s2w1, bufQ, 65536, 128, 128, 6, 7);
  gemmf(bufQ, s2w2, bufP, 65536, 128, 256, 7, 8);
  applymax_k(bufP, 8, 1024, 64, 256, f2);

  // ---- SA3 (group_all): concat[xyz2,f2] -> 256 -> 512 -> 1024 -> maxpool ----
  build_x3_kernel<<<(1024 * 259 + 255) / 256, 256, 0, stream>>>(xyz2, f2, x3);
  float* Y3a = bufQ;
  float* Y3b = bufQ + 262144;
  float* Y3c = bufQ + 786432;
  gemm0(x3, s3w0, Y3a, 1024, 259, 256, 9);
  gemmf(Y3a, s3w1, Y3b, 1024, 256, 512, 9, 10);
  gemmf(Y3b, s3w2, Y3c, 1024, 512, 1024, 10, 11);
  applymax_k(Y3c, 11, 8, 128, 1024, objf);

  // ---- head ----
  head_kernel<<<1, 512, 0, stream>>>(gfeat, objf, hw0, hb0, hw1, hb1, hw2, hb2, out);
}